// Round 1
// baseline (239.072 us; speedup 1.0000x reference)
//
#include <hip/hip_runtime.h>

// Problem constants
constexpr int kB = 8;
constexpr int kN = 256;
constexpr int kD = 1024;
constexpr int kP = 512;
constexpr int kM = kB * kN;  // 2048 rows

// ---------------------------------------------------------------------------
// proj_kernel: out[r][p] = act( sum_d x[r][d] * W[p][d] + bias[p] )
// z=0: Wl (+bl, linear) -> left;  z=1: Wr (no bias) -> right
// z=2: Ws1 (+bs1, relu) -> hs;    z=3: We1 (+be1, relu) -> he
// Tiles: TM=64 rows, TN=64 p, TK=32. 256 threads, 4x4 micro-tile.
// ---------------------------------------------------------------------------
__global__ __launch_bounds__(256) void proj_kernel(
    const float* __restrict__ x,
    const float* __restrict__ Wl, const float* __restrict__ bl,
    const float* __restrict__ Wr,
    const float* __restrict__ Ws1, const float* __restrict__ bs1,
    const float* __restrict__ We1, const float* __restrict__ be1,
    float* __restrict__ out_left, float* __restrict__ out_right,
    float* __restrict__ out_hs,   float* __restrict__ out_he)
{
    const int z = blockIdx.z;
    const float* W;
    const float* bias;
    float* dst;
    bool relu;
    if (z == 0)      { W = Wl;  bias = bl;      dst = out_left;  relu = false; }
    else if (z == 1) { W = Wr;  bias = nullptr; dst = out_right; relu = false; }
    else if (z == 2) { W = Ws1; bias = bs1;     dst = out_hs;    relu = true;  }
    else             { W = We1; bias = be1;     dst = out_he;    relu = true;  }

    // transposed LDS tiles: [kk][row], pad +4 floats -> 2-way conflict (free)
    __shared__ float xs[32][68];
    __shared__ float wsm[32][68];

    const int r0 = blockIdx.x * 64;
    const int p0 = blockIdx.y * 64;
    const int t  = threadIdx.x;
    const int tp = t & 15;   // p micro-col group (x4)
    const int tr = t >> 4;   // r micro-row group (x4)

    float acc[4][4];
#pragma unroll
    for (int i = 0; i < 4; ++i)
#pragma unroll
        for (int j = 0; j < 4; ++j) acc[i][j] = 0.f;

    const int lrow = t >> 3;  // 0..31
    const int lkq  = t & 7;   // k-quad 0..7 (covers 32 k)

    for (int k0 = 0; k0 < kD; k0 += 32) {
#pragma unroll
        for (int pass = 0; pass < 2; ++pass) {
            const int row = lrow + pass * 32;
            const float4 v = *reinterpret_cast<const float4*>(
                &x[(size_t)(r0 + row) * kD + k0 + lkq * 4]);
            xs[lkq * 4 + 0][row] = v.x;
            xs[lkq * 4 + 1][row] = v.y;
            xs[lkq * 4 + 2][row] = v.z;
            xs[lkq * 4 + 3][row] = v.w;
            const float4 w = *reinterpret_cast<const float4*>(
                &W[(size_t)(p0 + row) * kD + k0 + lkq * 4]);
            wsm[lkq * 4 + 0][row] = w.x;
            wsm[lkq * 4 + 1][row] = w.y;
            wsm[lkq * 4 + 2][row] = w.z;
            wsm[lkq * 4 + 3][row] = w.w;
        }
        __syncthreads();
#pragma unroll
        for (int kk = 0; kk < 32; ++kk) {
            const float4 xa = *reinterpret_cast<const float4*>(&xs[kk][tr * 4]);
            const float4 wa = *reinterpret_cast<const float4*>(&wsm[kk][tp * 4]);
            const float xv[4] = {xa.x, xa.y, xa.z, xa.w};
            const float wv[4] = {wa.x, wa.y, wa.z, wa.w};
#pragma unroll
            for (int i = 0; i < 4; ++i)
#pragma unroll
                for (int j = 0; j < 4; ++j)
                    acc[i][j] = fmaf(xv[i], wv[j], acc[i][j]);
        }
        __syncthreads();
    }

    // bias quad for this thread's p columns
    float4 bq = make_float4(0.f, 0.f, 0.f, 0.f);
    if (bias) bq = *reinterpret_cast<const float4*>(&bias[p0 + tp * 4]);

#pragma unroll
    for (int i = 0; i < 4; ++i) {
        const int r = r0 + tr * 4 + i;
        float4 o;
        o.x = acc[i][0] + bq.x;
        o.y = acc[i][1] + bq.y;
        o.z = acc[i][2] + bq.z;
        o.w = acc[i][3] + bq.w;
        if (relu) {
            o.x = fmaxf(o.x, 0.f); o.y = fmaxf(o.y, 0.f);
            o.z = fmaxf(o.z, 0.f); o.w = fmaxf(o.w, 0.f);
        }
        *reinterpret_cast<float4*>(&dst[(size_t)r * kP + p0 + tp * 4]) = o;
    }
}

// ---------------------------------------------------------------------------
// head_kernel: start[r] = sum_p hs[r][p]*Ws2[p] + bs2 ; same for end.
// One wave per row, 4 waves/block.
// ---------------------------------------------------------------------------
__global__ __launch_bounds__(256) void head_kernel(
    const float* __restrict__ hs, const float* __restrict__ Ws2,
    const float* __restrict__ bs2,
    const float* __restrict__ he, const float* __restrict__ We2,
    const float* __restrict__ be2,
    float* __restrict__ out_start, float* __restrict__ out_end)
{
    const int wave = threadIdx.x >> 6;
    const int lane = threadIdx.x & 63;
    const int r = blockIdx.x * 4 + wave;
    float ss = 0.f, ee = 0.f;
#pragma unroll
    for (int p = lane; p < kP; p += 64) {
        ss = fmaf(hs[(size_t)r * kP + p], Ws2[p], ss);
        ee = fmaf(he[(size_t)r * kP + p], We2[p], ee);
    }
#pragma unroll
    for (int off = 32; off > 0; off >>= 1) {
        ss += __shfl_down(ss, off);
        ee += __shfl_down(ee, off);
    }
    if (lane == 0) {
        out_start[r] = ss + bs2[0];
        out_end[r]   = ee + be2[0];
    }
}

// ---------------------------------------------------------------------------
// bigram_kernel: out[b][i][j] = sum_p relu(left[b][j][p] + right[b][i][p]) * Wo[p] + bo
// 32x32 (i,j) tiles, P chunked by 64, transposed LDS [p][row].
// 256 threads = 16(tj) x 16(ti), 2x2 micro-tile.
// ---------------------------------------------------------------------------
__global__ __launch_bounds__(256) void bigram_kernel(
    const float* __restrict__ left, const float* __restrict__ right,
    const float* __restrict__ Wo, const float* __restrict__ bo,
    float* __restrict__ out)
{
    const int b  = blockIdx.z;
    const int i0 = blockIdx.y * 32;
    const int j0 = blockIdx.x * 32;

    __shared__ float ls[64][36];  // [p][j]
    __shared__ float rs[64][36];  // [p][i]
    __shared__ float wos[64];

    const int t  = threadIdx.x;
    const int tj = t & 15;
    const int ti = t >> 4;

    float acc00 = 0.f, acc01 = 0.f, acc10 = 0.f, acc11 = 0.f;

    const float* lbase = left  + ((size_t)b * kN + j0) * kP;
    const float* rbase = right + ((size_t)b * kN + i0) * kP;

    const int lrow = t >> 3;  // 0..31
    const int lkq  = t & 7;   // 0..7

    for (int pc = 0; pc < kP; pc += 64) {
#pragma unroll
        for (int h = 0; h < 2; ++h) {
            const int q = lkq + h * 8;  // float4 index 0..15 within 64-k chunk
            const float4 v = *reinterpret_cast<const float4*>(
                &lbase[(size_t)lrow * kP + pc + q * 4]);
            ls[q * 4 + 0][lrow] = v.x;
            ls[q * 4 + 1][lrow] = v.y;
            ls[q * 4 + 2][lrow] = v.z;
            ls[q * 4 + 3][lrow] = v.w;
            const float4 w = *reinterpret_cast<const float4*>(
                &rbase[(size_t)lrow * kP + pc + q * 4]);
            rs[q * 4 + 0][lrow] = w.x;
            rs[q * 4 + 1][lrow] = w.y;
            rs[q * 4 + 2][lrow] = w.z;
            rs[q * 4 + 3][lrow] = w.w;
        }
        if (t < 64) wos[t] = Wo[pc + t];
        __syncthreads();
#pragma unroll
        for (int kk = 0; kk < 64; ++kk) {
            const float wo = wos[kk];
            const float2 lv = *reinterpret_cast<const float2*>(&ls[kk][tj * 2]);
            const float2 rv = *reinterpret_cast<const float2*>(&rs[kk][ti * 2]);
            acc00 = fmaf(fmaxf(rv.x + lv.x, 0.f), wo, acc00);
            acc01 = fmaf(fmaxf(rv.x + lv.y, 0.f), wo, acc01);
            acc10 = fmaf(fmaxf(rv.y + lv.x, 0.f), wo, acc10);
            acc11 = fmaf(fmaxf(rv.y + lv.y, 0.f), wo, acc11);
        }
        __syncthreads();
    }

    const float bias = bo[0];
    const int i = i0 + ti * 2;
    const int j = j0 + tj * 2;
    out[((size_t)b * kN + i)     * kN + j]     = acc00 + bias;
    out[((size_t)b * kN + i)     * kN + j + 1] = acc01 + bias;
    out[((size_t)b * kN + i + 1) * kN + j]     = acc10 + bias;
    out[((size_t)b * kN + i + 1) * kN + j + 1] = acc11 + bias;
}

// ---------------------------------------------------------------------------
extern "C" void kernel_launch(void* const* d_in, const int* in_sizes, int n_in,
                              void* d_out, int out_size, void* d_ws, size_t ws_size,
                              hipStream_t stream) {
    const float* x   = (const float*)d_in[0];
    const float* Wl  = (const float*)d_in[1];
    const float* bl  = (const float*)d_in[2];
    const float* Wr  = (const float*)d_in[3];
    const float* Wo  = (const float*)d_in[4];
    const float* bo  = (const float*)d_in[5];
    const float* Ws1 = (const float*)d_in[6];
    const float* bs1 = (const float*)d_in[7];
    const float* Ws2 = (const float*)d_in[8];
    const float* bs2 = (const float*)d_in[9];
    const float* We1 = (const float*)d_in[10];
    const float* be1 = (const float*)d_in[11];
    const float* We2 = (const float*)d_in[12];
    const float* be2 = (const float*)d_in[13];

    float* out        = (float*)d_out;
    float* out_bigram = out;                               // [B,N,N,1] = 524288
    float* out_start  = out + (size_t)kB * kN * kN;        // [B,N,1]   = 2048
    float* out_end    = out_start + (size_t)kB * kN;       // [B,N,1]   = 2048

    // workspace layout: left | right | hs | he  (each M*P f32 = 4 MB)
    float* ws_left  = (float*)d_ws;
    float* ws_right = ws_left  + (size_t)kM * kP;
    float* ws_hs    = ws_right + (size_t)kM * kP;
    float* ws_he    = ws_hs    + (size_t)kM * kP;

    proj_kernel<<<dim3(kM / 64, kP / 64, 4), 256, 0, stream>>>(
        x, Wl, bl, Wr, Ws1, bs1, We1, be1,
        ws_left, ws_right, ws_hs, ws_he);

    head_kernel<<<dim3(kM / 4), 256, 0, stream>>>(
        ws_hs, Ws2, bs2, ws_he, We2, be2, out_start, out_end);

    bigram_kernel<<<dim3(kN / 32, kN / 32, kB), 256, 0, stream>>>(
        ws_left, ws_right, Wo, bo, out_bigram);
}

// Round 2
// 159.052 us; speedup vs baseline: 1.5031x; 1.5031x over previous
//
#include <hip/hip_runtime.h>

typedef __attribute__((ext_vector_type(8))) short short8;   // 8 bf16 (4 VGPRs)
typedef __attribute__((ext_vector_type(4))) float f32x4;    // MFMA accumulator

constexpr int kB = 8;
constexpr int kN = 256;
constexpr int kD = 1024;
constexpr int kP = 512;
constexpr int kM = kB * kN;  // 2048

// ---------------------------------------------------------------------------
// cvt_kernel: fp32 -> bf16 (RTNE) for x and the 4 projection weights.
// 524288 groups of 8 floats. xb: 2M elems, wb: 4 x 512K elems.
// ---------------------------------------------------------------------------
__global__ __launch_bounds__(256) void cvt_kernel(
    const float* __restrict__ x,
    const float* __restrict__ Wl, const float* __restrict__ Wr,
    const float* __restrict__ Ws1, const float* __restrict__ We1,
    unsigned short* __restrict__ xb, unsigned short* __restrict__ wb)
{
    const int g = blockIdx.x * 256 + threadIdx.x;  // 0..524287
    const float* src;
    unsigned short* dst;
    if (g < 262144) {
        src = x + (size_t)g * 8;
        dst = xb + (size_t)g * 8;
    } else {
        const int gg = g - 262144;
        const int w = gg >> 16;        // which weight
        const int r = gg & 65535;      // group within weight
        const float* s = (w == 0) ? Wl : (w == 1) ? Wr : (w == 2) ? Ws1 : We1;
        src = s + (size_t)r * 8;
        dst = wb + ((size_t)w << 19) + (size_t)r * 8;
    }
    const float4 a = *reinterpret_cast<const float4*>(src);
    const float4 b = *reinterpret_cast<const float4*>(src + 4);
    const float v[8] = {a.x, a.y, a.z, a.w, b.x, b.y, b.z, b.w};
    short8 o;
#pragma unroll
    for (int i = 0; i < 8; ++i) {
        unsigned u = __float_as_uint(v[i]);
        u = u + 0x7FFF + ((u >> 16) & 1);  // RTNE
        o[i] = (short)(u >> 16);
    }
    *reinterpret_cast<short8*>(dst) = o;
}

// ---------------------------------------------------------------------------
// proj_mfma: out[r][p] = act( sum_d xb[r][d] * W[p][d] + bias[p] )
// bf16 MFMA 16x16x32. Tile BM=128, BN=64, BK=32. 256 threads = 4 waves (2x2).
// Each wave: 64x32 output = 4(m) x 2(n) fragments.
// z=0 -> left_t (transposed [b][p][j]), z=1 -> right_t (transposed),
// z=2 -> hs [r][p] relu, z=3 -> he [r][p] relu.
// ---------------------------------------------------------------------------
__global__ __launch_bounds__(256) void proj_mfma(
    const unsigned short* __restrict__ xb, const unsigned short* __restrict__ wb,
    const float* __restrict__ bl, const float* __restrict__ bs1,
    const float* __restrict__ be1,
    float* __restrict__ left_t, float* __restrict__ right_t,
    float* __restrict__ hs, float* __restrict__ he)
{
    const int z = blockIdx.z;
    const unsigned short* W = wb + ((size_t)z << 19);
    const float* bias = (z == 0) ? bl : (z == 2) ? bs1 : (z == 3) ? be1 : nullptr;
    float* dst = (z == 0) ? left_t : (z == 1) ? right_t : (z == 2) ? hs : he;
    const bool relu = (z >= 2);
    const bool transp = (z < 2);

    __shared__ unsigned short As[128 * 32];  // 8 KB, row-major [row][k]
    __shared__ unsigned short Bs[64 * 32];   // 4 KB

    const int r0 = blockIdx.x * 128;
    const int p0 = blockIdx.y * 64;
    const int t = threadIdx.x;
    const int wid = t >> 6;
    const int lane = t & 63;
    const int wr = wid >> 1;  // 0..1
    const int wc = wid & 1;   // 0..1

    f32x4 acc[4][2] = {};

    // staging addresses: per call each lane deposits 16B at wavebase + lane*16
    const int lrow = lane >> 2;        // 0..15
    const int lcol = (lane & 3) * 8;   // bf16 col
    const unsigned short* gA0 = xb + (size_t)(r0 + wid * 16 + lrow) * kD + lcol;
    const unsigned short* gA1 = gA0 + (size_t)64 * kD;
    const unsigned short* gB  = W  + (size_t)(p0 + wid * 16 + lrow) * kD + lcol;
    char* lA0 = (char*)As + wid * 1024;
    char* lA1 = (char*)As + 4096 + wid * 1024;
    char* lB  = (char*)Bs + wid * 1024;

    for (int k0 = 0; k0 < kD; k0 += 32) {
        __builtin_amdgcn_global_load_lds(
            (const __attribute__((address_space(1))) void*)(gA0 + k0),
            (__attribute__((address_space(3))) void*)lA0, 16, 0, 0);
        __builtin_amdgcn_global_load_lds(
            (const __attribute__((address_space(1))) void*)(gA1 + k0),
            (__attribute__((address_space(3))) void*)lA1, 16, 0, 0);
        __builtin_amdgcn_global_load_lds(
            (const __attribute__((address_space(1))) void*)(gB + k0),
            (__attribute__((address_space(3))) void*)lB, 16, 0, 0);
        __syncthreads();

        short8 a[4], b[2];
#pragma unroll
        for (int m = 0; m < 4; ++m)
            a[m] = *reinterpret_cast<const short8*>(
                &As[(wr * 64 + m * 16 + (lane & 15)) * 32 + (lane >> 4) * 8]);
#pragma unroll
        for (int n = 0; n < 2; ++n)
            b[n] = *reinterpret_cast<const short8*>(
                &Bs[(wc * 32 + n * 16 + (lane & 15)) * 32 + (lane >> 4) * 8]);
#pragma unroll
        for (int m = 0; m < 4; ++m)
#pragma unroll
            for (int n = 0; n < 2; ++n)
                acc[m][n] = __builtin_amdgcn_mfma_f32_16x16x32_bf16(
                    a[m], b[n], acc[m][n], 0, 0, 0);
        __syncthreads();
    }

    // epilogue: C/D layout col=lane&15, row=(lane>>4)*4+reg  [m89]
    const int bb = r0 >> 8;  // batch (128-row block never crosses a 256 boundary)
#pragma unroll
    for (int n = 0; n < 2; ++n) {
        const int p = p0 + wc * 32 + n * 16 + (lane & 15);
        const float bv = bias ? bias[p] : 0.f;
#pragma unroll
        for (int m = 0; m < 4; ++m) {
            const f32x4 c = acc[m][n];
            const int rbase = r0 + wr * 64 + m * 16 + (lane >> 4) * 4;
#pragma unroll
            for (int q = 0; q < 4; ++q) {
                float v = c[q] + bv;
                if (relu) v = fmaxf(v, 0.f);
                const int r = rbase + q;
                if (transp)
                    dst[((size_t)bb * kP + p) * kN + (r & 255)] = v;
                else
                    dst[(size_t)r * kP + p] = v;
            }
        }
    }
}

// ---------------------------------------------------------------------------
// head_kernel: start[r] = sum_p hs[r][p]*Ws2[p] + bs2 ; same for end.
// ---------------------------------------------------------------------------
__global__ __launch_bounds__(256) void head_kernel(
    const float* __restrict__ hs, const float* __restrict__ Ws2,
    const float* __restrict__ bs2,
    const float* __restrict__ he, const float* __restrict__ We2,
    const float* __restrict__ be2,
    float* __restrict__ out_start, float* __restrict__ out_end)
{
    const int wave = threadIdx.x >> 6;
    const int lane = threadIdx.x & 63;
    const int r = blockIdx.x * 4 + wave;
    float ss = 0.f, ee = 0.f;
#pragma unroll
    for (int p = lane; p < kP; p += 64) {
        ss = fmaf(hs[(size_t)r * kP + p], Ws2[p], ss);
        ee = fmaf(he[(size_t)r * kP + p], We2[p], ee);
    }
#pragma unroll
    for (int off = 32; off > 0; off >>= 1) {
        ss += __shfl_down(ss, off);
        ee += __shfl_down(ee, off);
    }
    if (lane == 0) {
        out_start[r] = ss + bs2[0];
        out_end[r]   = ee + be2[0];
    }
}

// ---------------------------------------------------------------------------
// bigram_kernel: out[b][i][j] = sum_p relu(left[b][j][p]+right[b][i][p])*Wo[p]+bo
// Inputs pre-transposed: left_t[b][p][j], right_t[b][p][i] -> staging is a
// straight contiguous copy (no LDS transpose, no conflicts).
// Tile: 32(i) x 64(j), P chunked by 64. 256 threads = 16(tj) x 16(ti),
// micro-tile 2(i) x 4(j) -> 3 VALU ops + 3 LDS bytes per output-cell-p.
// ---------------------------------------------------------------------------
__global__ __launch_bounds__(256) void bigram_kernel(
    const float* __restrict__ left_t, const float* __restrict__ right_t,
    const float* __restrict__ Wo, const float* __restrict__ bo,
    float* __restrict__ out)
{
    const int b  = blockIdx.z;
    const int i0 = blockIdx.y * 32;
    const int j0 = blockIdx.x * 64;

    __shared__ float ls[64][64];  // [p][j]
    __shared__ float rs[64][32];  // [p][i]
    __shared__ float wos[64];

    const int t  = threadIdx.x;
    const int tj = t & 15;
    const int ti = t >> 4;

    float acc[2][4] = {};

    const float* lb = left_t  + (size_t)b * kP * kN + j0;
    const float* rb = right_t + (size_t)b * kP * kN + i0;

    for (int pc = 0; pc < kP; pc += 64) {
#pragma unroll
        for (int h = 0; h < 4; ++h) {  // ls: 4096 floats
            const int idx = h * 256 + t;
            const int pp = idx >> 4, jq = idx & 15;
            *reinterpret_cast<float4*>(&ls[pp][jq * 4]) =
                *reinterpret_cast<const float4*>(&lb[(size_t)(pc + pp) * kN + jq * 4]);
        }
#pragma unroll
        for (int h = 0; h < 2; ++h) {  // rs: 2048 floats
            const int idx = h * 256 + t;
            const int pp = idx >> 3, iq = idx & 7;
            *reinterpret_cast<float4*>(&rs[pp][iq * 4]) =
                *reinterpret_cast<const float4*>(&rb[(size_t)(pc + pp) * kN + iq * 4]);
        }
        if (t < 64) wos[t] = Wo[pc + t];
        __syncthreads();

#pragma unroll 16
        for (int kk = 0; kk < 64; ++kk) {
            const float wo = wos[kk];
            const float4 lv = *reinterpret_cast<const float4*>(&ls[kk][tj * 4]);
            const float2 rv = *reinterpret_cast<const float2*>(&rs[kk][ti * 2]);
            const float lvv[4] = {lv.x, lv.y, lv.z, lv.w};
            const float rvv[2] = {rv.x, rv.y};
#pragma unroll
            for (int ii = 0; ii < 2; ++ii)
#pragma unroll
                for (int jj = 0; jj < 4; ++jj)
                    acc[ii][jj] = fmaf(fmaxf(rvv[ii] + lvv[jj], 0.f), wo, acc[ii][jj]);
        }
        __syncthreads();
    }

    const float bias = bo[0];
#pragma unroll
    for (int ii = 0; ii < 2; ++ii) {
        const int i = i0 + ti * 2 + ii;
        float4 o;
        o.x = acc[ii][0] + bias;
        o.y = acc[ii][1] + bias;
        o.z = acc[ii][2] + bias;
        o.w = acc[ii][3] + bias;
        *reinterpret_cast<float4*>(&out[((size_t)b * kN + i) * kN + j0 + tj * 4]) = o;
    }
}

// ---------------------------------------------------------------------------
extern "C" void kernel_launch(void* const* d_in, const int* in_sizes, int n_in,
                              void* d_out, int out_size, void* d_ws, size_t ws_size,
                              hipStream_t stream) {
    const float* x   = (const float*)d_in[0];
    const float* Wl  = (const float*)d_in[1];
    const float* bl  = (const float*)d_in[2];
    const float* Wr  = (const float*)d_in[3];
    const float* Wo  = (const float*)d_in[4];
    const float* bo  = (const float*)d_in[5];
    const float* Ws1 = (const float*)d_in[6];
    const float* bs1 = (const float*)d_in[7];
    const float* Ws2 = (const float*)d_in[8];
    const float* bs2 = (const float*)d_in[9];
    const float* We1 = (const float*)d_in[10];
    const float* be1 = (const float*)d_in[11];
    const float* We2 = (const float*)d_in[12];
    const float* be2 = (const float*)d_in[13];

    float* out        = (float*)d_out;
    float* out_bigram = out;                          // [B,N,N,1]
    float* out_start  = out + (size_t)kB * kN * kN;   // [B,N,1]
    float* out_end    = out_start + (size_t)kB * kN;  // [B,N,1]

    // ws layout: xb (4MB bf16) | wb (4MB bf16 x4 weights) | 4 x 4MB fp32
    unsigned short* xb = (unsigned short*)d_ws;
    unsigned short* wb = xb + (size_t)2097152;
    float* left_t  = (float*)((char*)d_ws + (size_t)8 * 1024 * 1024);
    float* right_t = left_t  + (size_t)kM * kP;
    float* hs      = right_t + (size_t)kM * kP;
    float* he      = hs      + (size_t)kM * kP;

    cvt_kernel<<<2048, 256, 0, stream>>>(x, Wl, Wr, Ws1, We1, xb, wb);

    proj_mfma<<<dim3(kM / 128, kP / 64, 4), 256, 0, stream>>>(
        xb, wb, bl, bs1, be1, left_t, right_t, hs, he);

    head_kernel<<<kM / 4, 256, 0, stream>>>(
        hs, Ws2, bs2, he, We2, be2, out_start, out_end);

    bigram_kernel<<<dim3(kN / 64, kN / 32, kB), 256, 0, stream>>>(
        left_t, right_t, Wo, bo, out_bigram);
}

// Round 4
// 138.148 us; speedup vs baseline: 1.7306x; 1.1513x over previous
//
#include <hip/hip_runtime.h>
#include <hip/hip_fp16.h>

typedef __attribute__((ext_vector_type(8))) short short8;   // 8 bf16
typedef __attribute__((ext_vector_type(4))) float f32x4;    // MFMA acc

constexpr int kB = 8;
constexpr int kN = 256;
constexpr int kD = 1024;
constexpr int kP = 512;
constexpr int kM = kB * kN;  // 2048

// v_pk_max_f16 — ROCm headers lack __hmax2; emit the VOP3P op directly.
__device__ __forceinline__ __half2 pk_max2(__half2 a, __half2 b) {
    unsigned ua = *reinterpret_cast<unsigned*>(&a);
    unsigned ub = *reinterpret_cast<unsigned*>(&b);
    unsigned ur;
    asm("v_pk_max_f16 %0, %1, %2" : "=v"(ur) : "v"(ua), "v"(ub));
    return *reinterpret_cast<__half2*>(&ur);
}

// ---------------------------------------------------------------------------
// cvt_kernel: fp32 -> bf16 for x and the 4 projection weights (merged into
// one [2048][1024] matrix wb). Tail blocks (>=2048) init out_start/out_end
// with the head biases (proj_mfma atomicAdds partial head dots onto them).
// ---------------------------------------------------------------------------
__global__ __launch_bounds__(256) void cvt_kernel(
    const float* __restrict__ x,
    const float* __restrict__ Wl, const float* __restrict__ Wr,
    const float* __restrict__ Ws1, const float* __restrict__ We1,
    const float* __restrict__ bs2, const float* __restrict__ be2,
    unsigned short* __restrict__ xb, unsigned short* __restrict__ wb,
    float* __restrict__ out_start, float* __restrict__ out_end)
{
    const int bid = blockIdx.x;
    if (bid >= 2048) {  // head-bias init: 4096 elements
        const int idx = (bid - 2048) * 256 + threadIdx.x;
        if (idx < 2048) out_start[idx] = bs2[0];
        else            out_end[idx - 2048] = be2[0];
        return;
    }
    const int g = bid * 256 + threadIdx.x;  // 0..524287 groups of 8
    const float* src;
    unsigned short* dst;
    if (g < 262144) {
        src = x + (size_t)g * 8;
        dst = xb + (size_t)g * 8;
    } else {
        const int gg = g - 262144;
        const int w = gg >> 16;        // 0=Wl 1=Wr 2=Ws1 3=We1
        const int r = gg & 65535;
        const float* s = (w == 0) ? Wl : (w == 1) ? Wr : (w == 2) ? Ws1 : We1;
        src = s + (size_t)r * 8;
        dst = wb + ((size_t)w << 19) + (size_t)r * 8;
    }
    const float4 a = *reinterpret_cast<const float4*>(src);
    const float4 b = *reinterpret_cast<const float4*>(src + 4);
    const float v[8] = {a.x, a.y, a.z, a.w, b.x, b.y, b.z, b.w};
    short8 o;
#pragma unroll
    for (int i = 0; i < 8; ++i) {
        unsigned u = __float_as_uint(v[i]);
        u = u + 0x7FFF + ((u >> 16) & 1);  // RTNE
        o[i] = (short)(u >> 16);
    }
    *reinterpret_cast<short8*>(dst) = o;
}

// ---------------------------------------------------------------------------
// proj_mfma: merged GEMM  C[r][q] = sum_d xb[r][d] * wb[q][d],  q in [0,2048)
// z = q>>9: 0->left (bias bl, store f16 transposed [b][p][j])
//           1->right (no bias, f16 transposed)
//           2,3->heads: relu(+bs1/be1), dot with Ws2/We2, shfl-reduce,
//                atomicAdd into out_start/out_end (no intermediate buffer).
// BM=128 BN=64 BK=32, 4 waves (2x2), 4x2 fragments/wave, double-buffered LDS
// with ONE barrier per K-step (stage next -> compute cur -> sync).
// ---------------------------------------------------------------------------
__global__ __launch_bounds__(256) void proj_mfma(
    const unsigned short* __restrict__ xb, const unsigned short* __restrict__ wb,
    const float* __restrict__ bl, const float* __restrict__ bs1,
    const float* __restrict__ be1,
    const float* __restrict__ Ws2, const float* __restrict__ We2,
    __half* __restrict__ left_h, __half* __restrict__ right_h,
    float* __restrict__ out_start, float* __restrict__ out_end)
{
    __shared__ unsigned short As[2][128 * 32];  // 8 KB x2
    __shared__ unsigned short Bs[2][64 * 32];   // 4 KB x2

    const int r0 = blockIdx.x * 128;
    const int q0 = blockIdx.y * 64;
    const int z  = q0 >> 9;
    const int t = threadIdx.x, wid = t >> 6, lane = t & 63;
    const int wr = wid >> 1, wc = wid & 1;

    f32x4 acc[4][2] = {};

    const int lrow = lane >> 2, lcol = (lane & 3) * 8;
    const unsigned short* gA0 = xb + (size_t)(r0 + wid * 16 + lrow) * kD + lcol;
    const unsigned short* gA1 = gA0 + (size_t)64 * kD;
    const unsigned short* gB  = wb + (size_t)(q0 + wid * 16 + lrow) * kD + lcol;

#define STAGE(buf, k0) do { \
    __builtin_amdgcn_global_load_lds( \
        (const __attribute__((address_space(1))) void*)(gA0 + (k0)), \
        (__attribute__((address_space(3))) void*)((char*)&As[buf][0] + wid * 1024), 16, 0, 0); \
    __builtin_amdgcn_global_load_lds( \
        (const __attribute__((address_space(1))) void*)(gA1 + (k0)), \
        (__attribute__((address_space(3))) void*)((char*)&As[buf][0] + 4096 + wid * 1024), 16, 0, 0); \
    __builtin_amdgcn_global_load_lds( \
        (const __attribute__((address_space(1))) void*)(gB + (k0)), \
        (__attribute__((address_space(3))) void*)((char*)&Bs[buf][0] + wid * 1024), 16, 0, 0); \
} while (0)

    STAGE(0, 0);
    __syncthreads();
    int cur = 0;
    for (int k0 = 0; k0 < kD; k0 += 32) {
        if (k0 + 32 < kD) STAGE(cur ^ 1, k0 + 32);
        short8 a[4], b[2];
#pragma unroll
        for (int m = 0; m < 4; ++m)
            a[m] = *reinterpret_cast<const short8*>(
                &As[cur][(wr * 64 + m * 16 + (lane & 15)) * 32 + (lane >> 4) * 8]);
#pragma unroll
        for (int n = 0; n < 2; ++n)
            b[n] = *reinterpret_cast<const short8*>(
                &Bs[cur][(wc * 32 + n * 16 + (lane & 15)) * 32 + (lane >> 4) * 8]);
#pragma unroll
        for (int m = 0; m < 4; ++m)
#pragma unroll
            for (int n = 0; n < 2; ++n)
                acc[m][n] = __builtin_amdgcn_mfma_f32_16x16x32_bf16(
                    a[m], b[n], acc[m][n], 0, 0, 0);
        __syncthreads();
        cur ^= 1;
    }
#undef STAGE

    // C/D layout: col = lane&15, row = (lane>>4)*4 + reg  [m89]
    int pcol[2]; float bq[2];
#pragma unroll
    for (int n = 0; n < 2; ++n) {
        pcol[n] = (q0 & 511) + wc * 32 + n * 16 + (lane & 15);
        bq[n] = (z == 0) ? bl[pcol[n]] : (z == 2) ? bs1[pcol[n]]
              : (z == 3) ? be1[pcol[n]] : 0.f;
    }
    if (z < 2) {
        __half* dst = (z == 0) ? left_h : right_h;
        const int bb = r0 >> 8;
        const int jbase = (r0 & 255) + wr * 64 + (lane >> 4) * 4;
#pragma unroll
        for (int n = 0; n < 2; ++n) {
            __half* drow = dst + (size_t)(bb * kP + pcol[n]) * kN;
#pragma unroll
            for (int m = 0; m < 4; ++m) {
                const f32x4 c = acc[m][n];
                __half2 h01 = __floats2half2_rn(c[0] + bq[n], c[1] + bq[n]);
                __half2 h23 = __floats2half2_rn(c[2] + bq[n], c[3] + bq[n]);
                uint2 u;
                u.x = *reinterpret_cast<unsigned*>(&h01);
                u.y = *reinterpret_cast<unsigned*>(&h23);
                *reinterpret_cast<uint2*>(&drow[jbase + m * 16]) = u;
            }
        }
    } else {
        const float* Wv = (z == 2) ? Ws2 : We2;
        float* outh = (z == 2) ? out_start : out_end;
        const float w0 = Wv[pcol[0]], w1 = Wv[pcol[1]];
        const int rbase = r0 + wr * 64 + (lane >> 4) * 4;
#pragma unroll
        for (int m = 0; m < 4; ++m) {
#pragma unroll
            for (int q = 0; q < 4; ++q) {
                float s = fmaxf(acc[m][0][q] + bq[0], 0.f) * w0 +
                          fmaxf(acc[m][1][q] + bq[1], 0.f) * w1;
                s += __shfl_xor(s, 1); s += __shfl_xor(s, 2);
                s += __shfl_xor(s, 4); s += __shfl_xor(s, 8);
                if ((lane & 15) == 0)
                    atomicAdd(&outh[rbase + m * 16 + q], s);
            }
        }
    }
}

// ---------------------------------------------------------------------------
// bigram_kernel: partial[bz][i][j] = sum_{p in chunk pc} relu(l[j][p]+r[i][p])*Wo[p]
// bz = b*8 + pc (P split into 8 chunks of 64 -> 1024 blocks, 4/CU).
// f16 packed math: 2 cells per v_pk instruction. rs staged pre-duplicated
// {r,r}; ls pairs {l_j, l_j+1} read directly. Micro-tile 4i x 4j per thread.
// ---------------------------------------------------------------------------
__global__ __launch_bounds__(256) void bigram_kernel(
    const __half* __restrict__ left_h, const __half* __restrict__ right_h,
    const float* __restrict__ Wo, float* __restrict__ part)
{
    __shared__ __half ls[64][64];     // [p][j]  8 KB
    __shared__ __half2 rs2[64][64];   // [p][i] dup'd  16 KB
    __shared__ __half2 wos[64];

    const int bz = blockIdx.z, b = bz >> 3, pc = bz & 7;
    const int i0 = blockIdx.y * 64, j0 = blockIdx.x * 64;
    const int t = threadIdx.x, wid = t >> 6, lane = t & 63;
    const int tj = t & 15, ti = t >> 4;

    const __half* lbase = left_h  + (size_t)(b * kP + pc * 64) * kN;
    const __half* rbase = right_h + (size_t)(b * kP + pc * 64) * kN;

    // ls: direct global->LDS (linear dest, 1 KB per wave-call)
#pragma unroll
    for (int h = 0; h < 2; ++h) {
        const int row = wid * 16 + h * 8 + (lane >> 3);
        __builtin_amdgcn_global_load_lds(
            (const __attribute__((address_space(1))) void*)
                (lbase + (size_t)row * kN + j0 + (lane & 7) * 8),
            (__attribute__((address_space(3))) void*)
                ((char*)&ls[0][0] + wid * 2048 + h * 1024),
            16, 0, 0);
    }
    // rs2: reg-staged with in-register duplication {r,r}
    uint2 rload[4];
#pragma unroll
    for (int h = 0; h < 4; ++h) {
        const int idx = h * 256 + t, pp = idx >> 4, iq = idx & 15;
        rload[h] = *reinterpret_cast<const uint2*>(&rbase[(size_t)pp * kN + i0 + iq * 4]);
    }
    if (t < 64) wos[t] = __float2half2_rn(Wo[pc * 64 + t]);
#pragma unroll
    for (int h = 0; h < 4; ++h) {
        const int idx = h * 256 + t, pp = idx >> 4, iq = idx & 15;
        const unsigned lo = rload[h].x, hi = rload[h].y;
        uint4 d;
        d.x = (lo & 0xFFFFu) | (lo << 16);
        d.y = (lo >> 16)     | (lo & 0xFFFF0000u);
        d.z = (hi & 0xFFFFu) | (hi << 16);
        d.w = (hi >> 16)     | (hi & 0xFFFF0000u);
        *reinterpret_cast<uint4*>(&rs2[pp][iq * 4]) = d;
    }
    __syncthreads();

    const __half2 zero2 = __float2half2_rn(0.f);
    __half2 acc2[4][2];
#pragma unroll
    for (int ii = 0; ii < 4; ++ii)
#pragma unroll
        for (int jp = 0; jp < 2; ++jp) acc2[ii][jp] = zero2;

#pragma unroll 8
    for (int kk = 0; kk < 64; ++kk) {
        const __half2 wo2 = wos[kk];
        union { uint2 u; __half2 h[2]; } L;
        L.u = *reinterpret_cast<const uint2*>(&ls[kk][tj * 4]);
        union { uint4 u; __half2 h[4]; } R;
        R.u = *reinterpret_cast<const uint4*>(&rs2[kk][ti * 4]);
#pragma unroll
        for (int ii = 0; ii < 4; ++ii)
#pragma unroll
            for (int jp = 0; jp < 2; ++jp) {
                __half2 s = __hadd2(R.h[ii], L.h[jp]);
                s = pk_max2(s, zero2);
                acc2[ii][jp] = __hfma2(s, wo2, acc2[ii][jp]);
            }
    }

    float* po = part + (size_t)bz * 65536;
#pragma unroll
    for (int ii = 0; ii < 4; ++ii) {
        const float2 a = __half22float2(acc2[ii][0]);
        const float2 c = __half22float2(acc2[ii][1]);
        float4 o = {a.x, a.y, c.x, c.y};
        *reinterpret_cast<float4*>(&po[(i0 + ti * 4 + ii) * kN + j0 + tj * 4]) = o;
    }
}

// ---------------------------------------------------------------------------
// reduce_kernel: out[b][i][j] = bo + sum_{pc<8} part[b*8+pc][i][j]
// ---------------------------------------------------------------------------
__global__ __launch_bounds__(256) void reduce_kernel(
    const float* __restrict__ part, const float* __restrict__ bo,
    float* __restrict__ out)
{
    const int e4 = blockIdx.x * 256 + threadIdx.x;  // 0..131071
    const int e = e4 * 4, b = e >> 16, r = e & 65535;
    const float bias = bo[0];
    float4 acc = {bias, bias, bias, bias};
#pragma unroll
    for (int k = 0; k < 8; ++k) {
        const float4 v = *reinterpret_cast<const float4*>(
            &part[(size_t)(b * 8 + k) * 65536 + r]);
        acc.x += v.x; acc.y += v.y; acc.z += v.z; acc.w += v.w;
    }
    *reinterpret_cast<float4*>(&out[e]) = acc;
}

// ---------------------------------------------------------------------------
extern "C" void kernel_launch(void* const* d_in, const int* in_sizes, int n_in,
                              void* d_out, int out_size, void* d_ws, size_t ws_size,
                              hipStream_t stream) {
    const float* x   = (const float*)d_in[0];
    const float* Wl  = (const float*)d_in[1];
    const float* bl  = (const float*)d_in[2];
    const float* Wr  = (const float*)d_in[3];
    const float* Wo  = (const float*)d_in[4];
    const float* bo  = (const float*)d_in[5];
    const float* Ws1 = (const float*)d_in[6];
    const float* bs1 = (const float*)d_in[7];
    const float* Ws2 = (const float*)d_in[8];
    const float* bs2 = (const float*)d_in[9];
    const float* We1 = (const float*)d_in[10];
    const float* be1 = (const float*)d_in[11];
    const float* We2 = (const float*)d_in[12];
    const float* be2 = (const float*)d_in[13];

    float* out        = (float*)d_out;
    float* out_bigram = out;                          // [B,N,N,1]
    float* out_start  = out + (size_t)kB * kN * kN;   // [B,N,1]
    float* out_end    = out_start + (size_t)kB * kN;  // [B,N,1]

    // ws layout (20 MB total):
    //   0-2 MB   left_h  (f16, [b][p][j])
    //   2-4 MB   right_h (f16, [b][p][i])
    //   4-8 MB   xb (bf16)       } dead after proj_mfma
    //   8-12 MB  wb (bf16)       }
    //   4-20 MB  part (f32, 64x65536) -- aliases xb/wb, written by bigram
    __half* left_h  = (__half*)d_ws;
    __half* right_h = left_h + (size_t)1048576;
    unsigned short* xb = (unsigned short*)((char*)d_ws + (size_t)4 * 1024 * 1024);
    unsigned short* wb = xb + (size_t)2097152;
    float* part = (float*)((char*)d_ws + (size_t)4 * 1024 * 1024);

    cvt_kernel<<<2064, 256, 0, stream>>>(
        x, Wl, Wr, Ws1, We1, bs2, be2, xb, wb, out_start, out_end);

    proj_mfma<<<dim3(16, 32), 256, 0, stream>>>(
        xb, wb, bl, bs1, be1, Ws2, We2, left_h, right_h, out_start, out_end);

    bigram_kernel<<<dim3(4, 4, 64), 256, 0, stream>>>(
        left_h, right_h, Wo, part);

    reduce_kernel<<<512, 256, 0, stream>>>(part, bo, out_bigram);
}

// Round 5
// 128.313 us; speedup vs baseline: 1.8632x; 1.0767x over previous
//
#include <hip/hip_runtime.h>
#include <hip/hip_fp16.h>

typedef __attribute__((ext_vector_type(8))) short short8;   // 8 bf16
typedef __attribute__((ext_vector_type(4))) float f32x4;    // MFMA acc

constexpr int kB = 8;
constexpr int kN = 256;
constexpr int kD = 1024;
constexpr int kP = 512;
constexpr int kM = kB * kN;  // 2048

// v_pk_max_f16 — ROCm headers lack __hmax2; emit the VOP3P op directly.
__device__ __forceinline__ __half2 pk_max2(__half2 a, __half2 b) {
    unsigned ua = *reinterpret_cast<unsigned*>(&a);
    unsigned ub = *reinterpret_cast<unsigned*>(&b);
    unsigned ur;
    asm("v_pk_max_f16 %0, %1, %2" : "=v"(ur) : "v"(ua), "v"(ub));
    return *reinterpret_cast<__half2*>(&ur);
}

// ---------------------------------------------------------------------------
// cvt_kernel: fp32 -> bf16 for x and the 4 projection weights (merged into
// one [2048][1024] matrix wb). Tail blocks (>=2048) init out_start/out_end
// with the head biases (proj_mfma atomicAdds partial head dots onto them).
// ---------------------------------------------------------------------------
__global__ __launch_bounds__(256) void cvt_kernel(
    const float* __restrict__ x,
    const float* __restrict__ Wl, const float* __restrict__ Wr,
    const float* __restrict__ Ws1, const float* __restrict__ We1,
    const float* __restrict__ bs2, const float* __restrict__ be2,
    unsigned short* __restrict__ xb, unsigned short* __restrict__ wb,
    float* __restrict__ out_start, float* __restrict__ out_end)
{
    const int bid = blockIdx.x;
    if (bid >= 2048) {  // head-bias init: 4096 elements
        const int idx = (bid - 2048) * 256 + threadIdx.x;
        if (idx < 2048) out_start[idx] = bs2[0];
        else            out_end[idx - 2048] = be2[0];
        return;
    }
    const int g = bid * 256 + threadIdx.x;  // 0..524287 groups of 8
    const float* src;
    unsigned short* dst;
    if (g < 262144) {
        src = x + (size_t)g * 8;
        dst = xb + (size_t)g * 8;
    } else {
        const int gg = g - 262144;
        const int w = gg >> 16;        // 0=Wl 1=Wr 2=Ws1 3=We1
        const int r = gg & 65535;
        const float* s = (w == 0) ? Wl : (w == 1) ? Wr : (w == 2) ? Ws1 : We1;
        src = s + (size_t)r * 8;
        dst = wb + ((size_t)w << 19) + (size_t)r * 8;
    }
    const float4 a = *reinterpret_cast<const float4*>(src);
    const float4 b = *reinterpret_cast<const float4*>(src + 4);
    const float v[8] = {a.x, a.y, a.z, a.w, b.x, b.y, b.z, b.w};
    short8 o;
#pragma unroll
    for (int i = 0; i < 8; ++i) {
        unsigned u = __float_as_uint(v[i]);
        u = u + 0x7FFF + ((u >> 16) & 1);  // RTNE
        o[i] = (short)(u >> 16);
    }
    *reinterpret_cast<short8*>(dst) = o;
}

// ---------------------------------------------------------------------------
// proj_mfma: merged GEMM  C[r][q] = sum_d xb[r][d] * wb[q][d],  q in [0,2048)
// BM=BN=64, BK=64 -> grid 32x32 = 1024 blocks (4/CU).  4 waves (2x2), each
// wave a 32x32 output (2x2 fragments of 16x16x32, 2 k-subs per BK).
// LDS rows are 64 halves = 128 B -> XOR-swizzle byte^=(row&7)<<4 applied on
// BOTH sides (pre-swizzled global source for linear global_load_lds dest,
// swizzled ds_read addr) => conflict-free fragment reads (was 8-way).
// z = q0>>9: 0->left (bias bl, f16 transposed [b][p][j]); 1->right;
//            2,3->heads fused: relu(+bs1/be1), dot Ws2/We2, shfl-reduce,
//            atomicAdd into out_start/out_end.
// ---------------------------------------------------------------------------
__global__ __launch_bounds__(256) void proj_mfma(
    const unsigned short* __restrict__ xb, const unsigned short* __restrict__ wb,
    const float* __restrict__ bl, const float* __restrict__ bs1,
    const float* __restrict__ be1,
    const float* __restrict__ Ws2, const float* __restrict__ We2,
    __half* __restrict__ left_h, __half* __restrict__ right_h,
    float* __restrict__ out_start, float* __restrict__ out_end)
{
    __shared__ unsigned short As[2][64 * 64];  // 8 KB x2
    __shared__ unsigned short Bs[2][64 * 64];  // 8 KB x2

    const int r0 = blockIdx.x * 64;
    const int q0 = blockIdx.y * 64;
    const int z  = q0 >> 9;
    const int t = threadIdx.x, wid = t >> 6, lane = t & 63;
    const int wr = wid >> 1, wc = wid & 1;

    f32x4 acc[2][2] = {};

    // --- staging geometry (both-sides swizzle, rule #21) ---
    // wave-call c in {0,1}: LDS linear off = (wid*2+c)*1024 + lane*16
    //   -> row = (wid*2+c)*8 + (lane>>3), col-byte cb = (lane&7)*16
    // source col-byte = cb ^ ((row&7)<<4), row&7 == lane>>3
    const int srow0 = wid * 16 + (lane >> 3);          // call 0 row
    const int scolh = ((lane & 7) ^ (lane >> 3)) << 3; // swizzled col (halves)
    const unsigned short* gA0 = xb + (size_t)(r0 + srow0) * kD + scolh;
    const unsigned short* gA1 = gA0 + (size_t)8 * kD;  // call 1: +8 rows
    const unsigned short* gB0 = wb + (size_t)(q0 + srow0) * kD + scolh;
    const unsigned short* gB1 = gB0 + (size_t)8 * kD;

#define STAGE(buf, k0) do { \
    __builtin_amdgcn_global_load_lds( \
        (const __attribute__((address_space(1))) void*)(gA0 + (k0)), \
        (__attribute__((address_space(3))) void*)((char*)&As[buf][0] + wid * 2048), 16, 0, 0); \
    __builtin_amdgcn_global_load_lds( \
        (const __attribute__((address_space(1))) void*)(gA1 + (k0)), \
        (__attribute__((address_space(3))) void*)((char*)&As[buf][0] + wid * 2048 + 1024), 16, 0, 0); \
    __builtin_amdgcn_global_load_lds( \
        (const __attribute__((address_space(1))) void*)(gB0 + (k0)), \
        (__attribute__((address_space(3))) void*)((char*)&Bs[buf][0] + wid * 2048), 16, 0, 0); \
    __builtin_amdgcn_global_load_lds( \
        (const __attribute__((address_space(1))) void*)(gB1 + (k0)), \
        (__attribute__((address_space(3))) void*)((char*)&Bs[buf][0] + wid * 2048 + 1024), 16, 0, 0); \
} while (0)

    // --- fragment-read geometry (swizzled) ---
    // rowA(m) = wr*32 + m*16 + (lane&15); rowB(n) = wc*32 + n*16 + (lane&15)
    // logical col-byte = ks*64 + (lane>>4)*16; actual ^= (row&7)<<4, and
    // row&7 == lane&7 for all frags (bases are multiples of 8).
    const int sw = (lane & 7) << 4;
    const int cb0 = (lane >> 4) * 16;
    const int rA = wr * 32 + (lane & 15);
    const int rB = wc * 32 + (lane & 15);

    STAGE(0, 0);
    __syncthreads();
    int cur = 0;
    for (int k0 = 0; k0 < kD; k0 += 64) {
        if (k0 + 64 < kD) STAGE(cur ^ 1, k0 + 64);
        short8 a[2][2], b[2][2];
#pragma unroll
        for (int m = 0; m < 2; ++m)
#pragma unroll
            for (int ks = 0; ks < 2; ++ks) {
                a[m][ks] = *reinterpret_cast<const short8*>(
                    (const char*)&As[cur][0] +
                    (rA + m * 16) * 128 + ((ks * 64 + cb0) ^ sw));
                b[m][ks] = *reinterpret_cast<const short8*>(
                    (const char*)&Bs[cur][0] +
                    (rB + m * 16) * 128 + ((ks * 64 + cb0) ^ sw));
            }
#pragma unroll
        for (int m = 0; m < 2; ++m)
#pragma unroll
            for (int n = 0; n < 2; ++n)
#pragma unroll
                for (int ks = 0; ks < 2; ++ks)
                    acc[m][n] = __builtin_amdgcn_mfma_f32_16x16x32_bf16(
                        a[m][ks], b[n][ks], acc[m][n], 0, 0, 0);
        __syncthreads();
        cur ^= 1;
    }
#undef STAGE

    // C/D layout: col = lane&15, row = (lane>>4)*4 + reg  [m89]
    int pcol[2]; float bq[2];
#pragma unroll
    for (int n = 0; n < 2; ++n) {
        pcol[n] = (q0 & 511) + wc * 32 + n * 16 + (lane & 15);
        bq[n] = (z == 0) ? bl[pcol[n]] : (z == 2) ? bs1[pcol[n]]
              : (z == 3) ? be1[pcol[n]] : 0.f;
    }
    if (z < 2) {
        __half* dst = (z == 0) ? left_h : right_h;
        const int bb = r0 >> 8;
        const int jbase = (r0 & 255) + wr * 32 + (lane >> 4) * 4;
#pragma unroll
        for (int n = 0; n < 2; ++n) {
            __half* drow = dst + (size_t)(bb * kP + pcol[n]) * kN;
#pragma unroll
            for (int m = 0; m < 2; ++m) {
                const f32x4 c = acc[m][n];
                __half2 h01 = __floats2half2_rn(c[0] + bq[n], c[1] + bq[n]);
                __half2 h23 = __floats2half2_rn(c[2] + bq[n], c[3] + bq[n]);
                uint2 u;
                u.x = *reinterpret_cast<unsigned*>(&h01);
                u.y = *reinterpret_cast<unsigned*>(&h23);
                *reinterpret_cast<uint2*>(&drow[jbase + m * 16]) = u;
            }
        }
    } else {
        const float* Wv = (z == 2) ? Ws2 : We2;
        float* outh = (z == 2) ? out_start : out_end;
        const float w0 = Wv[pcol[0]], w1 = Wv[pcol[1]];
        const int rbase = r0 + wr * 32 + (lane >> 4) * 4;
#pragma unroll
        for (int m = 0; m < 2; ++m) {
#pragma unroll
            for (int q = 0; q < 4; ++q) {
                float s = fmaxf(acc[m][0][q] + bq[0], 0.f) * w0 +
                          fmaxf(acc[m][1][q] + bq[1], 0.f) * w1;
                s += __shfl_xor(s, 1); s += __shfl_xor(s, 2);
                s += __shfl_xor(s, 4); s += __shfl_xor(s, 8);
                if ((lane & 15) == 0)
                    atomicAdd(&outh[rbase + m * 16 + q], s);
            }
        }
    }
}

// ---------------------------------------------------------------------------
// bigram_kernel: partial[bz][i][j] = sum_{p in chunk pc} relu(l[j][p]+r[i][p])*Wo[p]
// bz = b*16 + pc (P split into 16 chunks of 32 -> 2048 blocks, 8/CU).
// f16 packed math: 2 cells per v_pk instruction. rs staged pre-duplicated
// {r,r}; ls pairs {l_j, l_j+1} read directly. Micro-tile 4i x 4j per thread.
// ---------------------------------------------------------------------------
__global__ __launch_bounds__(256) void bigram_kernel(
    const __half* __restrict__ left_h, const __half* __restrict__ right_h,
    const float* __restrict__ Wo, float* __restrict__ part)
{
    __shared__ __half ls[32][64];     // [p][j]  4 KB
    __shared__ __half2 rs2[32][64];   // [p][i] dup'd  8 KB
    __shared__ __half2 wos[32];

    const int bz = blockIdx.z, b = bz >> 4, pc = bz & 15;
    const int i0 = blockIdx.y * 64, j0 = blockIdx.x * 64;
    const int t = threadIdx.x, wid = t >> 6, lane = t & 63;
    const int tj = t & 15, ti = t >> 4;

    const __half* lbase = left_h  + (size_t)(b * kP + pc * 32) * kN;
    const __half* rbase = right_h + (size_t)(b * kP + pc * 32) * kN;

    // ls: direct global->LDS (linear dest, 1 KB per wave-call, 1 call/wave)
    {
        const int row = wid * 8 + (lane >> 3);
        __builtin_amdgcn_global_load_lds(
            (const __attribute__((address_space(1))) void*)
                (lbase + (size_t)row * kN + j0 + (lane & 7) * 8),
            (__attribute__((address_space(3))) void*)
                ((char*)&ls[0][0] + wid * 1024),
            16, 0, 0);
    }
    // rs2: reg-staged with in-register duplication {r,r}
    uint2 rload[2];
#pragma unroll
    for (int h = 0; h < 2; ++h) {
        const int idx = h * 256 + t, pp = idx >> 4, iq = idx & 15;
        rload[h] = *reinterpret_cast<const uint2*>(&rbase[(size_t)pp * kN + i0 + iq * 4]);
    }
    if (t < 32) wos[t] = __float2half2_rn(Wo[pc * 32 + t]);
#pragma unroll
    for (int h = 0; h < 2; ++h) {
        const int idx = h * 256 + t, pp = idx >> 4, iq = idx & 15;
        const unsigned lo = rload[h].x, hi = rload[h].y;
        uint4 d;
        d.x = (lo & 0xFFFFu) | (lo << 16);
        d.y = (lo >> 16)     | (lo & 0xFFFF0000u);
        d.z = (hi & 0xFFFFu) | (hi << 16);
        d.w = (hi >> 16)     | (hi & 0xFFFF0000u);
        *reinterpret_cast<uint4*>(&rs2[pp][iq * 4]) = d;
    }
    __syncthreads();

    const __half2 zero2 = __float2half2_rn(0.f);
    __half2 acc2[4][2];
#pragma unroll
    for (int ii = 0; ii < 4; ++ii)
#pragma unroll
        for (int jp = 0; jp < 2; ++jp) acc2[ii][jp] = zero2;

#pragma unroll 8
    for (int kk = 0; kk < 32; ++kk) {
        const __half2 wo2 = wos[kk];
        union { uint2 u; __half2 h[2]; } L;
        L.u = *reinterpret_cast<const uint2*>(&ls[kk][tj * 4]);
        union { uint4 u; __half2 h[4]; } R;
        R.u = *reinterpret_cast<const uint4*>(&rs2[kk][ti * 4]);
#pragma unroll
        for (int ii = 0; ii < 4; ++ii)
#pragma unroll
            for (int jp = 0; jp < 2; ++jp) {
                __half2 s = __hadd2(R.h[ii], L.h[jp]);
                s = pk_max2(s, zero2);
                acc2[ii][jp] = __hfma2(s, wo2, acc2[ii][jp]);
            }
    }

    float* po = part + (size_t)bz * 65536;
#pragma unroll
    for (int ii = 0; ii < 4; ++ii) {
        const float2 a = __half22float2(acc2[ii][0]);
        const float2 c = __half22float2(acc2[ii][1]);
        float4 o = {a.x, a.y, c.x, c.y};
        *reinterpret_cast<float4*>(&po[(i0 + ti * 4 + ii) * kN + j0 + tj * 4]) = o;
    }
}

// ---------------------------------------------------------------------------
// reduce_kernel: out[b][i][j] = bo + sum_{pc<16} part[b*16+pc][i][j]
// ---------------------------------------------------------------------------
__global__ __launch_bounds__(256) void reduce_kernel(
    const float* __restrict__ part, const float* __restrict__ bo,
    float* __restrict__ out)
{
    const int e4 = blockIdx.x * 256 + threadIdx.x;  // 0..131071
    const int e = e4 * 4, b = e >> 16, r = e & 65535;
    const float bias = bo[0];
    float4 acc = {bias, bias, bias, bias};
#pragma unroll
    for (int k = 0; k < 16; ++k) {
        const float4 v = *reinterpret_cast<const float4*>(
            &part[(size_t)(b * 16 + k) * 65536 + r]);
        acc.x += v.x; acc.y += v.y; acc.z += v.z; acc.w += v.w;
    }
    *reinterpret_cast<float4*>(&out[e]) = acc;
}

// ---------------------------------------------------------------------------
extern "C" void kernel_launch(void* const* d_in, const int* in_sizes, int n_in,
                              void* d_out, int out_size, void* d_ws, size_t ws_size,
                              hipStream_t stream) {
    const float* x   = (const float*)d_in[0];
    const float* Wl  = (const float*)d_in[1];
    const float* bl  = (const float*)d_in[2];
    const float* Wr  = (const float*)d_in[3];
    const float* Wo  = (const float*)d_in[4];
    const float* bo  = (const float*)d_in[5];
    const float* Ws1 = (const float*)d_in[6];
    const float* bs1 = (const float*)d_in[7];
    const float* Ws2 = (const float*)d_in[8];
    const float* bs2 = (const float*)d_in[9];
    const float* We1 = (const float*)d_in[10];
    const float* be1 = (const float*)d_in[11];
    const float* We2 = (const float*)d_in[12];
    const float* be2 = (const float*)d_in[13];

    float* out        = (float*)d_out;
    float* out_bigram = out;                          // [B,N,N,1]
    float* out_start  = out + (size_t)kB * kN * kN;   // [B,N,1]
    float* out_end    = out_start + (size_t)kB * kN;  // [B,N,1]

    // ws layout (36 MB total):
    //   0-2 MB   left_h  (f16, [b][p][j])
    //   2-4 MB   right_h (f16, [b][p][i])
    //   4-8 MB   xb (bf16)       } dead after proj_mfma
    //   8-12 MB  wb (bf16)       }
    //   4-36 MB  part (f32, 128x65536) -- aliases xb/wb, written by bigram
    __half* left_h  = (__half*)d_ws;
    __half* right_h = left_h + (size_t)1048576;
    unsigned short* xb = (unsigned short*)((char*)d_ws + (size_t)4 * 1024 * 1024);
    unsigned short* wb = xb + (size_t)2097152;
    float* part = (float*)((char*)d_ws + (size_t)4 * 1024 * 1024);

    cvt_kernel<<<2064, 256, 0, stream>>>(
        x, Wl, Wr, Ws1, We1, bs2, be2, xb, wb, out_start, out_end);

    proj_mfma<<<dim3(32, 32), 256, 0, stream>>>(
        xb, wb, bl, bs1, be1, Ws2, We2, left_h, right_h, out_start, out_end);

    bigram_kernel<<<dim3(4, 4, 128), 256, 0, stream>>>(
        left_h, right_h, Wo, part);

    reduce_kernel<<<512, 256, 0, stream>>>(part, bo, out_bigram);
}